// Round 2
// baseline (170.529 us; speedup 1.0000x reference)
//
#include <hip/hip_runtime.h>

#define H_DIM 2048
#define W_DIM 4096
#define N_ELEM (H_DIM * W_DIM * 3)
#define N_PIX  (H_DIM * W_DIM)

// ---------------- Pass 1: global max of inputs (all values >= 0) ----------------
// Exact partition: 4096 blocks x 256 threads = 1048576 threads; n4 = 6291456 = 6 per thread.
__global__ __launch_bounds__(256) void max_reduce_kernel(const float* __restrict__ in,
                                                         unsigned int* __restrict__ ws) {
    const float4* in4 = (const float4*)in;
    const int stride = 4096 * 256;
    int i = blockIdx.x * blockDim.x + threadIdx.x;
    // 6 independent loads in flight
    float4 a = in4[i];
    float4 b = in4[i + stride];
    float4 c = in4[i + 2 * stride];
    float4 d = in4[i + 3 * stride];
    float4 e = in4[i + 4 * stride];
    float4 f = in4[i + 5 * stride];
    float m0 = fmaxf(fmaxf(a.x, a.y), fmaxf(a.z, a.w));
    float m1 = fmaxf(fmaxf(b.x, b.y), fmaxf(b.z, b.w));
    float m2 = fmaxf(fmaxf(c.x, c.y), fmaxf(c.z, c.w));
    float m3 = fmaxf(fmaxf(d.x, d.y), fmaxf(d.z, d.w));
    float m4 = fmaxf(fmaxf(e.x, e.y), fmaxf(e.z, e.w));
    float m5 = fmaxf(fmaxf(f.x, f.y), fmaxf(f.z, f.w));
    float m = fmaxf(fmaxf(fmaxf(m0, m1), fmaxf(m2, m3)), fmaxf(m4, m5));

    #pragma unroll
    for (int off = 32; off > 0; off >>= 1)
        m = fmaxf(m, __shfl_down(m, off, 64));
    __shared__ float smax[4];
    int lane = threadIdx.x & 63;
    int wave = threadIdx.x >> 6;
    if (lane == 0) smax[wave] = m;
    __syncthreads();
    if (threadIdx.x == 0) {
        float bm = fmaxf(fmaxf(smax[0], smax[1]), fmaxf(smax[2], smax[3]));
        atomicMax(ws, __float_as_uint(bm));  // valid ordering for non-negative floats
    }
}

// ---------------- Pass 2: elastic warp, 4 pixels per thread ----------------
__global__ __launch_bounds__(256) void elastic_sample_kernel(const float* __restrict__ in,
                                                             const float* __restrict__ disp,
                                                             const unsigned int* __restrict__ wsmax,
                                                             float* __restrict__ out) {
    int t = blockIdx.x * blockDim.x + threadIdx.x;   // 0 .. N_PIX/4
    int y  = t >> 10;                                 // 4096/4 = 1024 groups per row
    int xg = (t & 1023) << 2;

    float cval = __uint_as_float(*wsmax);

    const float sy = 2.0f / (float)(H_DIM - 1);
    const float sx = 2.0f / (float)(W_DIM - 1);
    float uy = (float)y * sy;                 // [0,2]
    int iy = min((int)uy, 1);
    float fyc = uy - (float)iy;

    // y-blended control rows (x3 control points), scaled by 5; same for all 4 pixels
    float cr0[3], cr1[3];
    #pragma unroll
    for (int k = 0; k < 3; k++) {
        cr0[k] = 5.0f * ((1.0f - fyc) * disp[iy * 3 + k]     + fyc * disp[(iy + 1) * 3 + k]);
        cr1[k] = 5.0f * ((1.0f - fyc) * disp[9 + iy * 3 + k] + fyc * disp[9 + (iy + 1) * 3 + k]);
    }

    float o[12];
    #pragma unroll
    for (int px = 0; px < 4; px++) {
        int x = xg + px;
        float ux = (float)x * sx;
        int ix = min((int)ux, 1);
        float fxc = ux - (float)ix;
        float dy = (1.0f - fxc) * cr0[ix] + fxc * cr0[ix + 1];
        float dx = (1.0f - fxc) * cr1[ix] + fxc * cr1[ix + 1];

        float cy = (float)y + dy;
        float cx = (float)x + dx;
        float y0f = floorf(cy);
        float x0f = floorf(cx);
        float fy = cy - y0f;
        float fx = cx - x0f;
        int y0 = (int)y0f;
        int x0 = (int)x0f;

        float acc0 = 0.0f, acc1 = 0.0f, acc2 = 0.0f;
        #pragma unroll
        for (int j = 0; j < 2; j++) {
            #pragma unroll
            for (int i = 0; i < 2; i++) {
                int yy = y0 + j;
                int xx = x0 + i;
                bool valid = (yy >= 0) & (yy < H_DIM) & (xx >= 0) & (xx < W_DIM);
                int yc = min(max(yy, 0), H_DIM - 1);
                int xc = min(max(xx, 0), W_DIM - 1);
                const float* p = in + ((size_t)yc * W_DIM + xc) * 3;
                float w = (j ? fy : (1.0f - fy)) * (i ? fx : (1.0f - fx));
                float s0 = valid ? p[0] : cval;
                float s1 = valid ? p[1] : cval;
                float s2 = valid ? p[2] : cval;
                acc0 = fmaf(w, s0, acc0);
                acc1 = fmaf(w, s1, acc1);
                acc2 = fmaf(w, s2, acc2);
            }
        }
        o[px * 3 + 0] = acc0;
        o[px * 3 + 1] = acc1;
        o[px * 3 + 2] = acc2;
    }

    float* ob = out + (size_t)t * 12;   // 48B-aligned
    float4 v0 = make_float4(o[0], o[1], o[2], o[3]);
    float4 v1 = make_float4(o[4], o[5], o[6], o[7]);
    float4 v2 = make_float4(o[8], o[9], o[10], o[11]);
    ((float4*)ob)[0] = v0;
    ((float4*)ob)[1] = v1;
    ((float4*)ob)[2] = v2;
}

extern "C" void kernel_launch(void* const* d_in, const int* in_sizes, int n_in,
                              void* d_out, int out_size, void* d_ws, size_t ws_size,
                              hipStream_t stream) {
    const float* in   = (const float*)d_in[0];   // [2048, 4096, 3] f32
    const float* disp = (const float*)d_in[1];   // [2, 3, 3] f32
    float* out = (float*)d_out;
    unsigned int* wsmax = (unsigned int*)d_ws;

    hipMemsetAsync(d_ws, 0, sizeof(unsigned int), stream);

    max_reduce_kernel<<<4096, 256, 0, stream>>>(in, wsmax);

    int blocks = (N_PIX / 4) / 256;  // 8192
    elastic_sample_kernel<<<blocks, 256, 0, stream>>>(in, disp, wsmax, out);
}

// Round 3
// 64.873 us; speedup vs baseline: 2.6286x; 2.6286x over previous
//
#include <hip/hip_runtime.h>

#define H_DIM 2048
#define W_DIM 4096
#define N_ELEM (H_DIM * W_DIM * 3)
#define N_PIX  (H_DIM * W_DIM)

// ---------------- Pass 1: global max (inputs >= 0) ----------------
// 512 blocks x 256 threads = 131072 threads; 6291456 float4 total = 48/thread.
// 6 iters x 8 independent loads in flight; ONE atomic per block (512 total).
__global__ __launch_bounds__(256) void max_reduce_kernel(const float* __restrict__ in,
                                                         unsigned int* __restrict__ ws) {
    const float4* __restrict__ in4 = (const float4*)in;
    int t = blockIdx.x * 256 + threadIdx.x;     // 0 .. 131071
    float m = 0.0f;
    #pragma unroll
    for (int j = 0; j < 6; j++) {
        float4 v[8];
        #pragma unroll
        for (int k = 0; k < 8; k++)
            v[k] = in4[t + (j * 8 + k) * 131072];
        #pragma unroll
        for (int k = 0; k < 8; k++)
            m = fmaxf(m, fmaxf(fmaxf(v[k].x, v[k].y), fmaxf(v[k].z, v[k].w)));
    }
    #pragma unroll
    for (int off = 32; off > 0; off >>= 1)
        m = fmaxf(m, __shfl_down(m, off, 64));
    __shared__ float smax[4];
    int lane = threadIdx.x & 63;
    int wave = threadIdx.x >> 6;
    if (lane == 0) smax[wave] = m;
    __syncthreads();
    if (threadIdx.x == 0) {
        float bm = fmaxf(fmaxf(smax[0], smax[1]), fmaxf(smax[2], smax[3]));
        atomicMax(ws, __float_as_uint(bm));  // valid for non-negative floats
    }
}

// ---------------- Pass 2: elastic warp, 1 px/thread, merged window loads ----------------
struct F3 { float a, b, c; };   // 12B, align 4

__global__ __launch_bounds__(256) void elastic_sample_kernel(const float* __restrict__ in,
                                                             const float* __restrict__ disp,
                                                             const unsigned int* __restrict__ wsmax,
                                                             float* __restrict__ out) {
    __shared__ __align__(16) float obuf[768];   // 256 px * 3 ch
    int tid = threadIdx.x;
    int t = blockIdx.x * 256 + tid;
    int y = t >> 12;                 // W = 4096
    int x = t & (W_DIM - 1);

    float cval = __uint_as_float(*wsmax);

    // 3x3 control-grid bilinear -> dense displacement
    float uy = (float)y * (2.0f / (float)(H_DIM - 1));
    float ux = (float)x * (2.0f / (float)(W_DIM - 1));
    int iy = min((int)uy, 1);
    int ix = min((int)ux, 1);
    float fyc = uy - (float)iy;
    float fxc = ux - (float)ix;

    const float* dp0 = disp + iy * 3 + ix;        // channel 0 (dy)
    const float* dp1 = dp0 + 9;                   // channel 1 (dx)
    float dy = 5.0f * ((1.0f - fyc) * ((1.0f - fxc) * dp0[0] + fxc * dp0[1])
                     +         fyc  * ((1.0f - fxc) * dp0[3] + fxc * dp0[4]));
    float dx = 5.0f * ((1.0f - fyc) * ((1.0f - fxc) * dp1[0] + fxc * dp1[1])
                     +         fyc  * ((1.0f - fxc) * dp1[3] + fxc * dp1[4]));

    float cy = (float)y + dy;
    float cx = (float)x + dx;
    float y0f = floorf(cy);
    float x0f = floorf(cx);
    float fy = cy - y0f;
    float fx = cx - x0f;
    int y0 = (int)y0f;
    int x0 = (int)x0f;

    // x window: 6 contiguous floats starting at clamp(x0, 0, W-2); always in-row & in-buffer.
    int xbase = min(max(x0, 0), W_DIM - 2);
    bool sel = (x0 == xbase);              // corner0 at L0 (else corner0=L1, corner1=L0)
    bool vx0 = (x0 >= 0) & (x0 <= W_DIM - 1);
    bool vx1 = (x0 >= -1) & (x0 <= W_DIM - 2);

    float acc0 = 0.0f, acc1 = 0.0f, acc2 = 0.0f;
    #pragma unroll
    for (int j = 0; j < 2; j++) {
        int yy = y0 + j;
        bool vy = (yy >= 0) & (yy < H_DIM);
        int yr = min(max(yy, 0), H_DIM - 1);
        const float* p = in + ((size_t)yr * W_DIM + xbase) * 3;
        F3 L0 = *(const F3*)p;
        F3 L1 = *(const F3*)(p + 3);

        float wj = j ? fy : (1.0f - fy);
        float w0 = wj * (1.0f - fx);
        float w1 = wj * fx;
        bool v0 = vy & vx0;
        bool v1 = vy & vx1;

        float c0a = sel ? L0.a : L1.a;  float c1a = sel ? L1.a : L0.a;
        float c0b = sel ? L0.b : L1.b;  float c1b = sel ? L1.b : L0.b;
        float c0c = sel ? L0.c : L1.c;  float c1c = sel ? L1.c : L0.c;
        c0a = v0 ? c0a : cval;  c1a = v1 ? c1a : cval;
        c0b = v0 ? c0b : cval;  c1b = v1 ? c1b : cval;
        c0c = v0 ? c0c : cval;  c1c = v1 ? c1c : cval;

        acc0 = fmaf(w0, c0a, fmaf(w1, c1a, acc0));
        acc1 = fmaf(w0, c0b, fmaf(w1, c1b, acc1));
        acc2 = fmaf(w0, c0c, fmaf(w1, c1c, acc2));
    }

    // pack through LDS -> dense float4 stores
    obuf[tid * 3 + 0] = acc0;
    obuf[tid * 3 + 1] = acc1;
    obuf[tid * 3 + 2] = acc2;
    __syncthreads();
    if (tid < 192) {
        float4 v = ((const float4*)obuf)[tid];
        ((float4*)out)[(size_t)blockIdx.x * 192 + tid] = v;
    }
}

extern "C" void kernel_launch(void* const* d_in, const int* in_sizes, int n_in,
                              void* d_out, int out_size, void* d_ws, size_t ws_size,
                              hipStream_t stream) {
    const float* in   = (const float*)d_in[0];   // [2048, 4096, 3] f32
    const float* disp = (const float*)d_in[1];   // [2, 3, 3] f32
    float* out = (float*)d_out;
    unsigned int* wsmax = (unsigned int*)d_ws;

    hipMemsetAsync(d_ws, 0, sizeof(unsigned int), stream);

    max_reduce_kernel<<<512, 256, 0, stream>>>(in, wsmax);

    elastic_sample_kernel<<<N_PIX / 256, 256, 0, stream>>>(in, disp, wsmax, out);
}

// Round 4
// 64.453 us; speedup vs baseline: 2.6458x; 1.0065x over previous
//
#include <hip/hip_runtime.h>

#define H_DIM 2048
#define W_DIM 4096
#define ROWF  (W_DIM * 3)          // floats per input row = 12288
#define ROW4  (ROWF / 4)           // float4 per input row = 3072
#define NROW_CAP 8
#define NPX_CAP  272               // staged pixel columns (multiple of 4)
#define NF_CAP   (NPX_CAP * 3)     // 816 floats per staged row
#define NF4_CAP  (NF_CAP / 4)      // 204 float4 per staged row

// ---------------- Pass 1: global max (inputs >= 0) ----------------
__global__ __launch_bounds__(256) void max_reduce_kernel(const float* __restrict__ in,
                                                         unsigned int* __restrict__ ws) {
    const float4* __restrict__ in4 = (const float4*)in;
    int t = blockIdx.x * 256 + threadIdx.x;     // 512 blocks -> 131072 threads, 48 f4/thread
    float m = 0.0f;
    #pragma unroll
    for (int j = 0; j < 6; j++) {
        float4 v[8];
        #pragma unroll
        for (int k = 0; k < 8; k++) v[k] = in4[t + (j * 8 + k) * 131072];
        #pragma unroll
        for (int k = 0; k < 8; k++)
            m = fmaxf(m, fmaxf(fmaxf(v[k].x, v[k].y), fmaxf(v[k].z, v[k].w)));
    }
    #pragma unroll
    for (int off = 32; off > 0; off >>= 1)
        m = fmaxf(m, __shfl_down(m, off, 64));
    __shared__ float smax[4];
    if ((threadIdx.x & 63) == 0) smax[threadIdx.x >> 6] = m;
    __syncthreads();
    if (threadIdx.x == 0)
        atomicMax(ws, __float_as_uint(fmaxf(fmaxf(smax[0], smax[1]), fmaxf(smax[2], smax[3]))));
}

// displacement at pixel (y fixed via iy/fyc, x = xx); same FP ops as per-pixel reference path
__device__ __forceinline__ void eval_disp(const float* __restrict__ disp,
                                          int iy, float fyc, int xx,
                                          float& dy, float& dx) {
    float ux = (float)xx * (2.0f / 4095.0f);
    int ix = min((int)ux, 1);
    float fxc = ux - (float)ix;
    const float* dp0 = disp + iy * 3 + ix;
    const float* dp1 = dp0 + 9;
    dy = 5.0f * ((1.0f - fyc) * ((1.0f - fxc) * dp0[0] + fxc * dp0[1])
               +          fyc  * ((1.0f - fxc) * dp0[3] + fxc * dp0[4]));
    dx = 5.0f * ((1.0f - fyc) * ((1.0f - fxc) * dp1[0] + fxc * dp1[1])
               +          fyc  * ((1.0f - fxc) * dp1[3] + fxc * dp1[4]));
}

// ---------------- Pass 2: LDS-staged elastic warp ----------------
// One block = 256 consecutive pixels of one output row (16 blocks/row, 32768 blocks).
// Each block lies in exactly ONE control cell (x=2048 boundary is block-aligned), so
// dy(x), dx(x) are linear in x: bounds from endpoints; cx strictly monotone (|slope|<1).
__global__ __launch_bounds__(256) void elastic_sample_kernel(const float* __restrict__ in,
                                                             const float* __restrict__ disp,
                                                             const unsigned int* __restrict__ wsmax,
                                                             float* __restrict__ out) {
    __shared__ __align__(16) float stage[NROW_CAP * NF_CAP];   // 26112 B
    const int tid = threadIdx.x;
    const int bid = blockIdx.x;
    const int y  = bid >> 4;
    const int xs = (bid & 15) << 8;
    const int x  = xs + tid;

    const float cval = __uint_as_float(*wsmax);

    // block-uniform y-cell
    float uy = (float)y * (2.0f / 2047.0f);
    int iy = min((int)uy, 1);
    float fyc = uy - (float)iy;

    // endpoints -> slope/intercept + bounds (all block-uniform)
    float dyA, dxA, dyB, dxB;
    eval_disp(disp, iy, fyc, xs,        dyA, dxA);
    eval_disp(disp, iy, fyc, xs + 255,  dyB, dxB);
    float sY = (dyB - dyA) * (1.0f / 255.0f);
    float sX = (dxB - dxA) * (1.0f / 255.0f);

    float cyMin = (float)y + fminf(dyA, dyB);
    float cyMax = (float)y + fmaxf(dyA, dyB);
    float cxMin = (float)xs + dxA;             // cx monotone increasing in x
    float cxMax = (float)(xs + 255) + dxB;

    int ymin_s = (int)floorf(cyMin);
    int nrows  = (int)floorf(cyMax) - ymin_s + 2;        // rows [ymin_s, ymin_s+nrows)
    int xmin_s = ((int)floorf(cxMin)) & ~3;              // align to 4 px (float4 grid)
    int npx    = (int)floorf(cxMax) + 2 - xmin_s;        // cols [xmin_s, xmin_s+npx)
    bool fits  = (nrows <= NROW_CAP) && (npx <= NPX_CAP);

    // per-pixel displacement (linear): tiny FP wiggle vs endpoints covered by index clamps
    float dy = fmaf((float)tid, sY, dyA);
    float dx = fmaf((float)tid, sX, dxA);
    float cy = (float)y + dy;
    float cx = (float)x + dx;
    float y0f = floorf(cy);
    float x0f = floorf(cx);
    float fy = cy - y0f;
    float fx = cx - x0f;
    int y0 = (int)y0f;
    int x0 = (int)x0f;

    float s00a, s00b, s00c, s01a, s01b, s01c;
    float s10a, s10b, s10c, s11a, s11b, s11c;

    if (fits) {
        // ---- stage: contiguous float4 rows; OOB slots filled with cval ----
        int nf4 = (npx * 3 + 3) >> 2;          // <= 204 < 256: one chunk/thread/row
        int gb4 = (xmin_s * 3) / 4;            // exact (xmin_s multiple of 4)
        bool tload = tid < nf4;
        int c4 = gb4 + tid;
        bool cOOB = (c4 < 0) | (c4 >= ROW4);   // chunks align to the 0/12288 boundaries
        int c4c = min(max(c4, 0), ROW4 - 1);

        float4 tv[NROW_CAP];
        #pragma unroll
        for (int r = 0; r < NROW_CAP; r++) {
            if (r < nrows && tload) {
                int yc = min(max(ymin_s + r, 0), H_DIM - 1);
                tv[r] = ((const float4*)in)[(size_t)yc * ROW4 + c4c];
            }
        }
        #pragma unroll
        for (int r = 0; r < NROW_CAP; r++) {
            if (r < nrows && tload) {
                bool rOOB = ((ymin_s + r) < 0) | ((ymin_s + r) >= H_DIM);
                bool oob = rOOB | cOOB;
                float4 v = tv[r];
                if (oob) { v.x = cval; v.y = cval; v.z = cval; v.w = cval; }
                ((float4*)stage)[r * NF4_CAP + tid] = v;
            }
        }
        __syncthreads();

        // ---- gather from LDS (no validity masks needed: OOB slots hold cval) ----
        int r0 = min(max(y0 - ymin_s, 0), nrows - 2);
        int j0 = min(max(x0 - xmin_s, 0), npx - 2);
        const float* p0 = stage + r0 * NF_CAP + j0 * 3;
        const float* p1 = p0 + NF_CAP;
        s00a = p0[0]; s00b = p0[1]; s00c = p0[2];
        s01a = p0[3]; s01b = p0[4]; s01c = p0[5];
        s10a = p1[0]; s10b = p1[1]; s10c = p1[2];
        s11a = p1[3]; s11b = p1[4]; s11c = p1[5];
    } else {
        // ---- fallback: direct clamped global gather with masks (block-uniform branch) ----
        bool vy0 = (y0 >= 0) & (y0 < H_DIM);
        bool vy1 = (y0 >= -1) & (y0 < H_DIM - 1);
        bool vx0 = (x0 >= 0) & (x0 < W_DIM);
        bool vx1 = (x0 >= -1) & (x0 < W_DIM - 1);
        int yc0 = min(max(y0, 0), H_DIM - 1);
        int yc1 = min(max(y0 + 1, 0), H_DIM - 1);
        int xc0 = min(max(x0, 0), W_DIM - 1);
        int xc1 = min(max(x0 + 1, 0), W_DIM - 1);
        const float* q00 = in + ((size_t)yc0 * W_DIM + xc0) * 3;
        const float* q01 = in + ((size_t)yc0 * W_DIM + xc1) * 3;
        const float* q10 = in + ((size_t)yc1 * W_DIM + xc0) * 3;
        const float* q11 = in + ((size_t)yc1 * W_DIM + xc1) * 3;
        bool v00 = vy0 & vx0, v01 = vy0 & vx1, v10 = vy1 & vx0, v11 = vy1 & vx1;
        s00a = v00 ? q00[0] : cval; s00b = v00 ? q00[1] : cval; s00c = v00 ? q00[2] : cval;
        s01a = v01 ? q01[0] : cval; s01b = v01 ? q01[1] : cval; s01c = v01 ? q01[2] : cval;
        s10a = v10 ? q10[0] : cval; s10b = v10 ? q10[1] : cval; s10c = v10 ? q10[2] : cval;
        s11a = v11 ? q11[0] : cval; s11b = v11 ? q11[1] : cval; s11c = v11 ? q11[2] : cval;
    }

    float g0 = 1.0f - fy, h0 = 1.0f - fx;
    float w00 = g0 * h0, w01 = g0 * fx, w10 = fy * h0, w11 = fy * fx;

    float acc0 = fmaf(w00, s00a, fmaf(w01, s01a, fmaf(w10, s10a, w11 * s11a)));
    float acc1 = fmaf(w00, s00b, fmaf(w01, s01b, fmaf(w10, s10b, w11 * s11b)));
    float acc2 = fmaf(w00, s00c, fmaf(w01, s01c, fmaf(w10, s10c, w11 * s11c)));

    float* o = out + ((size_t)y * W_DIM + x) * 3;
    o[0] = acc0;
    o[1] = acc1;
    o[2] = acc2;
}

extern "C" void kernel_launch(void* const* d_in, const int* in_sizes, int n_in,
                              void* d_out, int out_size, void* d_ws, size_t ws_size,
                              hipStream_t stream) {
    const float* in   = (const float*)d_in[0];   // [2048, 4096, 3] f32
    const float* disp = (const float*)d_in[1];   // [2, 3, 3] f32
    float* out = (float*)d_out;
    unsigned int* wsmax = (unsigned int*)d_ws;

    hipMemsetAsync(d_ws, 0, sizeof(unsigned int), stream);

    max_reduce_kernel<<<512, 256, 0, stream>>>(in, wsmax);

    elastic_sample_kernel<<<32768, 256, 0, stream>>>(in, disp, wsmax, out);
}

// Round 6
// 62.455 us; speedup vs baseline: 2.7304x; 1.0320x over previous
//
#include <hip/hip_runtime.h>

#define H_DIM 2048
#define W_DIM 4096

typedef float fx4 __attribute__((ext_vector_type(4)));

// ws layout (floats): [0] = final max; [64 .. 64+1024) = per-block partials
#define WS_PART_OFF 64
#define MAXP_BLOCKS 1024

// ---------------- Pass 1a: per-block partial max (no atomics) ----------------
// 1024 blocks x 256 thr = 262144 threads; 6291456 float4 = 24/thread = 3 iters x 8 in flight.
__global__ __launch_bounds__(256) void max_partial_kernel(const float* __restrict__ in,
                                                          float* __restrict__ wsf) {
    const float4* __restrict__ in4 = (const float4*)in;
    int t = blockIdx.x * 256 + threadIdx.x;
    float m = 0.0f;
    #pragma unroll
    for (int j = 0; j < 3; j++) {
        float4 v[8];
        #pragma unroll
        for (int k = 0; k < 8; k++) v[k] = in4[t + (j * 8 + k) * (MAXP_BLOCKS * 256)];
        #pragma unroll
        for (int k = 0; k < 8; k++)
            m = fmaxf(m, fmaxf(fmaxf(v[k].x, v[k].y), fmaxf(v[k].z, v[k].w)));
    }
    #pragma unroll
    for (int off = 32; off > 0; off >>= 1)
        m = fmaxf(m, __shfl_down(m, off, 64));
    __shared__ float smax[4];
    if ((threadIdx.x & 63) == 0) smax[threadIdx.x >> 6] = m;
    __syncthreads();
    if (threadIdx.x == 0)
        wsf[WS_PART_OFF + blockIdx.x] = fmaxf(fmaxf(smax[0], smax[1]), fmaxf(smax[2], smax[3]));
}

// ---------------- Pass 1b: reduce 1024 partials -> wsf[0] ----------------
__global__ __launch_bounds__(256) void max_final_kernel(float* __restrict__ wsf) {
    const float4* p4 = (const float4*)(wsf + WS_PART_OFF);
    float4 v = p4[threadIdx.x];                    // 256 threads x 4 = 1024
    float m = fmaxf(fmaxf(v.x, v.y), fmaxf(v.z, v.w));
    #pragma unroll
    for (int off = 32; off > 0; off >>= 1)
        m = fmaxf(m, __shfl_down(m, off, 64));
    __shared__ float smax[4];
    if ((threadIdx.x & 63) == 0) smax[threadIdx.x >> 6] = m;
    __syncthreads();
    if (threadIdx.x == 0)
        wsf[0] = fmaxf(fmaxf(smax[0], smax[1]), fmaxf(smax[2], smax[3]));
}

// ---------------- Pass 2: elastic warp, XCD y-band swizzle, merged-window gather ----------------
struct F3 { float a, b, c; };   // 12B

__global__ __launch_bounds__(256) void elastic_sample_kernel(const float* __restrict__ in,
                                                             const float* __restrict__ disp,
                                                             const float* __restrict__ wsf,
                                                             float* __restrict__ out) {
    __shared__ __align__(16) float obuf[768];
    const int tid = threadIdx.x;
    // XCD swizzle: blocks with the same (bid & 7) land on one XCD (round-robin dispatch).
    // Give each XCD a contiguous 256-row band so y-overlap re-reads hit its private L2.
    int bid = blockIdx.x;
    int band = bid & 7;
    int idx = bid >> 3;                  // 0..4095 within band
    int y  = (band << 8) + (idx >> 4);   // band*256 + row-in-band
    int xs = (idx & 15) << 8;
    int x  = xs + tid;

    const float cval = wsf[0];

    // 3x3 control-grid bilinear -> per-pixel displacement (exact, as reference)
    float uy = (float)y * (2.0f / 2047.0f);
    float ux = (float)x * (2.0f / 4095.0f);
    int iy = min((int)uy, 1);
    int ix = min((int)ux, 1);
    float fyc = uy - (float)iy;
    float fxc = ux - (float)ix;
    const float* dp0 = disp + iy * 3 + ix;
    const float* dp1 = dp0 + 9;
    float dy = 5.0f * ((1.0f - fyc) * ((1.0f - fxc) * dp0[0] + fxc * dp0[1])
                     +         fyc  * ((1.0f - fxc) * dp0[3] + fxc * dp0[4]));
    float dx = 5.0f * ((1.0f - fyc) * ((1.0f - fxc) * dp1[0] + fxc * dp1[1])
                     +         fyc  * ((1.0f - fxc) * dp1[3] + fxc * dp1[4]));

    float cy = (float)y + dy;
    float cx = (float)x + dx;
    float y0f = floorf(cy);
    float x0f = floorf(cx);
    float fy = cy - y0f;
    float fx = cx - x0f;
    int y0 = (int)y0f;
    int x0 = (int)x0f;

    // merged x-window: 6 contiguous floats at clamp(x0,0,W-2); select remaps corners
    int xbase = min(max(x0, 0), W_DIM - 2);
    bool sel = (x0 == xbase);
    bool vx0 = (x0 >= 0) & (x0 <= W_DIM - 1);
    bool vx1 = (x0 >= -1) & (x0 <= W_DIM - 2);

    float acc0 = 0.0f, acc1 = 0.0f, acc2 = 0.0f;
    #pragma unroll
    for (int j = 0; j < 2; j++) {
        int yy = y0 + j;
        bool vy = (yy >= 0) & (yy < H_DIM);
        int yr = min(max(yy, 0), H_DIM - 1);
        const float* p = in + ((size_t)yr * W_DIM + xbase) * 3;
        F3 L0 = *(const F3*)p;
        F3 L1 = *(const F3*)(p + 3);

        float wj = j ? fy : (1.0f - fy);
        float w0 = wj * (1.0f - fx);
        float w1 = wj * fx;
        bool v0 = vy & vx0;
        bool v1 = vy & vx1;

        float c0a = sel ? L0.a : L1.a;  float c1a = sel ? L1.a : L0.a;
        float c0b = sel ? L0.b : L1.b;  float c1b = sel ? L1.b : L0.b;
        float c0c = sel ? L0.c : L1.c;  float c1c = sel ? L1.c : L0.c;
        c0a = v0 ? c0a : cval;  c1a = v1 ? c1a : cval;
        c0b = v0 ? c0b : cval;  c1b = v1 ? c1b : cval;
        c0c = v0 ? c0c : cval;  c1c = v1 ? c1c : cval;

        acc0 = fmaf(w0, c0a, fmaf(w1, c1a, acc0));
        acc1 = fmaf(w0, c0b, fmaf(w1, c1b, acc1));
        acc2 = fmaf(w0, c0c, fmaf(w1, c1c, acc2));
    }

    // pack via LDS -> dense non-temporal stores (don't pollute the L2 band)
    obuf[tid * 3 + 0] = acc0;
    obuf[tid * 3 + 1] = acc1;
    obuf[tid * 3 + 2] = acc2;
    __syncthreads();
    if (tid < 192) {
        fx4 v = ((const fx4*)obuf)[tid];
        fx4* dst = ((fx4*)out) + ((size_t)y * W_DIM + xs) * 3 / 4 + tid;
        __builtin_nontemporal_store(v, dst);
    }
}

extern "C" void kernel_launch(void* const* d_in, const int* in_sizes, int n_in,
                              void* d_out, int out_size, void* d_ws, size_t ws_size,
                              hipStream_t stream) {
    const float* in   = (const float*)d_in[0];   // [2048, 4096, 3] f32
    const float* disp = (const float*)d_in[1];   // [2, 3, 3] f32
    float* out = (float*)d_out;
    float* wsf = (float*)d_ws;

    max_partial_kernel<<<MAXP_BLOCKS, 256, 0, stream>>>(in, wsf);
    max_final_kernel<<<1, 256, 0, stream>>>(wsf);
    elastic_sample_kernel<<<32768, 256, 0, stream>>>(in, disp, wsf, out);
}

// Round 7
// 60.993 us; speedup vs baseline: 2.7959x; 1.0240x over previous
//
#include <hip/hip_runtime.h>

#define H_DIM 2048
#define W_DIM 4096

typedef float fx4 __attribute__((ext_vector_type(4)));
typedef float f3v __attribute__((ext_vector_type(3)));

// ws layout (floats): [0] = final max; [64 .. 64+1024) = per-block partials
#define WS_PART_OFF 64
#define MAXP_BLOCKS 1024

// ---------------- Pass 1a: per-block partial max (no atomics) ----------------
__global__ __launch_bounds__(256) void max_partial_kernel(const float* __restrict__ in,
                                                          float* __restrict__ wsf) {
    const float4* __restrict__ in4 = (const float4*)in;
    int t = blockIdx.x * 256 + threadIdx.x;
    float m = 0.0f;
    #pragma unroll
    for (int j = 0; j < 3; j++) {
        float4 v[8];
        #pragma unroll
        for (int k = 0; k < 8; k++) v[k] = in4[t + (j * 8 + k) * (MAXP_BLOCKS * 256)];
        #pragma unroll
        for (int k = 0; k < 8; k++)
            m = fmaxf(m, fmaxf(fmaxf(v[k].x, v[k].y), fmaxf(v[k].z, v[k].w)));
    }
    #pragma unroll
    for (int off = 32; off > 0; off >>= 1)
        m = fmaxf(m, __shfl_down(m, off, 64));
    __shared__ float smax[4];
    if ((threadIdx.x & 63) == 0) smax[threadIdx.x >> 6] = m;
    __syncthreads();
    if (threadIdx.x == 0)
        wsf[WS_PART_OFF + blockIdx.x] = fmaxf(fmaxf(smax[0], smax[1]), fmaxf(smax[2], smax[3]));
}

// ---------------- Pass 1b: reduce 1024 partials -> wsf[0] ----------------
__global__ __launch_bounds__(256) void max_final_kernel(float* __restrict__ wsf) {
    const float4* p4 = (const float4*)(wsf + WS_PART_OFF);
    float4 v = p4[threadIdx.x];
    float m = fmaxf(fmaxf(v.x, v.y), fmaxf(v.z, v.w));
    #pragma unroll
    for (int off = 32; off > 0; off >>= 1)
        m = fmaxf(m, __shfl_down(m, off, 64));
    __shared__ float smax[4];
    if ((threadIdx.x & 63) == 0) smax[threadIdx.x >> 6] = m;
    __syncthreads();
    if (threadIdx.x == 0)
        wsf[0] = fmaxf(fmaxf(smax[0], smax[1]), fmaxf(smax[2], smax[3]));
}

// ---------------- Pass 2: elastic warp; forced dwordx3 gathers ----------------
__global__ __launch_bounds__(256) void elastic_sample_kernel(const float* __restrict__ in,
                                                             const float* __restrict__ disp,
                                                             const float* __restrict__ wsf,
                                                             float* __restrict__ out) {
    __shared__ __align__(16) float obuf[768];
    const int tid = threadIdx.x;
    // XCD y-band swizzle (harmless, keeps L2 locality deterministic)
    int bid = blockIdx.x;
    int band = bid & 7;
    int idx = bid >> 3;
    int y  = (band << 8) + (idx >> 4);
    int xs = (idx & 15) << 8;
    int x  = xs + tid;

    const float cval = wsf[0];

    // 3x3 control-grid bilinear -> per-pixel displacement (exact, as reference)
    float uy = (float)y * (2.0f / 2047.0f);
    float ux = (float)x * (2.0f / 4095.0f);
    int iy = min((int)uy, 1);
    int ix = min((int)ux, 1);
    float fyc = uy - (float)iy;
    float fxc = ux - (float)ix;
    const float* dp0 = disp + iy * 3 + ix;
    const float* dp1 = dp0 + 9;
    float dy = 5.0f * ((1.0f - fyc) * ((1.0f - fxc) * dp0[0] + fxc * dp0[1])
                     +         fyc  * ((1.0f - fxc) * dp0[3] + fxc * dp0[4]));
    float dx = 5.0f * ((1.0f - fyc) * ((1.0f - fxc) * dp1[0] + fxc * dp1[1])
                     +         fyc  * ((1.0f - fxc) * dp1[3] + fxc * dp1[4]));

    float cy = (float)y + dy;
    float cx = (float)x + dx;
    float y0f = floorf(cy);
    float x0f = floorf(cx);
    float fy = cy - y0f;
    float fx = cx - x0f;
    int y0 = (int)y0f;
    int x0 = (int)x0f;

    // merged x-window: 6 contiguous floats at clamp(x0,0,W-2); sel remaps corners
    int xbase = min(max(x0, 0), W_DIM - 2);
    bool sel = (x0 == xbase);
    bool vx0 = (x0 >= 0) & (x0 <= W_DIM - 1);
    bool vx1 = (x0 >= -1) & (x0 <= W_DIM - 2);

    int yr0 = min(max(y0, 0), H_DIM - 1);
    int yr1 = min(max(y0 + 1, 0), H_DIM - 1);
    bool vy0 = (y0 >= 0) & (y0 < H_DIM);
    bool vy1 = (y0 + 1 >= 0) & (y0 + 1 < H_DIM);

    const float* p0 = in + ((size_t)yr0 * W_DIM + xbase) * 3;
    const float* p1 = in + ((size_t)yr1 * W_DIM + xbase) * 3;

    // Forced single-instruction 12B gathers (3 VGPRs each), two per row via offset:12.
    f3v L00, L01, L10, L11;
    asm volatile("global_load_dwordx3 %0, %4, off\n\t"
                 "global_load_dwordx3 %1, %4, off offset:12\n\t"
                 "global_load_dwordx3 %2, %5, off\n\t"
                 "global_load_dwordx3 %3, %5, off offset:12"
                 : "=&v"(L00), "=&v"(L01), "=&v"(L10), "=&v"(L11)
                 : "v"(p0), "v"(p1));
    asm volatile("s_waitcnt vmcnt(0)"
                 : "+v"(L00), "+v"(L01), "+v"(L10), "+v"(L11));
    __builtin_amdgcn_sched_barrier(0);

    float g0 = 1.0f - fy, h0 = 1.0f - fx;
    float w00 = g0 * h0, w01 = g0 * fx, w10 = fy * h0, w11 = fy * fx;

    float acc0, acc1, acc2;
    {
        // row 0 (y0): corner0 weight w00, corner1 weight w01
        float c0a = sel ? L00.x : L01.x;  float c1a = sel ? L01.x : L00.x;
        float c0b = sel ? L00.y : L01.y;  float c1b = sel ? L01.y : L00.y;
        float c0c = sel ? L00.z : L01.z;  float c1c = sel ? L01.z : L00.z;
        bool v0 = vy0 & vx0, v1 = vy0 & vx1;
        c0a = v0 ? c0a : cval;  c1a = v1 ? c1a : cval;
        c0b = v0 ? c0b : cval;  c1b = v1 ? c1b : cval;
        c0c = v0 ? c0c : cval;  c1c = v1 ? c1c : cval;
        acc0 = fmaf(w00, c0a, w01 * c1a);
        acc1 = fmaf(w00, c0b, w01 * c1b);
        acc2 = fmaf(w00, c0c, w01 * c1c);
    }
    {
        // row 1 (y0+1): weights w10, w11
        float c0a = sel ? L10.x : L11.x;  float c1a = sel ? L11.x : L10.x;
        float c0b = sel ? L10.y : L11.y;  float c1b = sel ? L11.y : L10.y;
        float c0c = sel ? L10.z : L11.z;  float c1c = sel ? L11.z : L10.z;
        bool v0 = vy1 & vx0, v1 = vy1 & vx1;
        c0a = v0 ? c0a : cval;  c1a = v1 ? c1a : cval;
        c0b = v0 ? c0b : cval;  c1b = v1 ? c1b : cval;
        c0c = v0 ? c0c : cval;  c1c = v1 ? c1c : cval;
        acc0 = fmaf(w10, c0a, fmaf(w11, c1a, acc0));
        acc1 = fmaf(w10, c0b, fmaf(w11, c1b, acc1));
        acc2 = fmaf(w10, c0c, fmaf(w11, c1c, acc2));
    }

    // pack via LDS -> dense non-temporal float4 stores
    obuf[tid * 3 + 0] = acc0;
    obuf[tid * 3 + 1] = acc1;
    obuf[tid * 3 + 2] = acc2;
    __syncthreads();
    if (tid < 192) {
        fx4 v = ((const fx4*)obuf)[tid];
        fx4* dst = ((fx4*)out) + ((size_t)y * W_DIM + xs) * 3 / 4 + tid;
        __builtin_nontemporal_store(v, dst);
    }
}

extern "C" void kernel_launch(void* const* d_in, const int* in_sizes, int n_in,
                              void* d_out, int out_size, void* d_ws, size_t ws_size,
                              hipStream_t stream) {
    const float* in   = (const float*)d_in[0];   // [2048, 4096, 3] f32
    const float* disp = (const float*)d_in[1];   // [2, 3, 3] f32
    float* out = (float*)d_out;
    float* wsf = (float*)d_ws;

    max_partial_kernel<<<MAXP_BLOCKS, 256, 0, stream>>>(in, wsf);
    max_final_kernel<<<1, 256, 0, stream>>>(wsf);
    elastic_sample_kernel<<<32768, 256, 0, stream>>>(in, disp, wsf, out);
}